// Round 18
// baseline (79.804 us; speedup 1.0000x reference)
//
#include <hip/hip_runtime.h>

#define N_NODES 100000
#define N_EDGES 1600000
#define HIDDEN 256

#define BSH 7                    // bucket = dst >> 7
#define BNODES 128               // nodes per bucket
#define NB 782                   // ceil(100000 / 128)
#define NPB 256                  // place blocks == sub-chunks per bucket == consumer block size
#define EPB 6250                 // edges per place block (256*6250 = 1.6M exact)
#define SLOTS 32                 // slots per (bucket, pblock): mean 8, P(ovf)~4e-13/pair
#define NCH 25000                // node-chunks of 4 rows (25000*4 = 100000 exact)
#define CPW 4                    // chunks per wave (pipeline depth amortization)
#define NZB 1563                 // z blocks: 1563*4 waves*4 chunks = 25008 >= 25000
#define RPAD 260                 // padded row stride (floats): rows hit distinct bank quads

// rec layout: [bucket][pblock][slot], 8B records {src(17b) | dstloc(7b)<<17, w}
// cnt layout: [bucket][pblock]  -> consumers read coalesced; fully overwritten each call
// W12 layout: SPLIT — W12[0..255] = col0, W12[256..511] = col1

// ---- K1: place (blocks 0..255) + W12/cvec fold (block 256) ----
__global__ __launch_bounds__(1024) void k_place(
        const int* __restrict__ ei, const float* __restrict__ ew,
        const float* __restrict__ W1, const float* __restrict__ b1,
        const float* __restrict__ W2, const float* __restrict__ b2,
        int* __restrict__ cnt, uint2* __restrict__ rec,
        float* __restrict__ W12, float* __restrict__ cvec) {
    const int tid = threadIdx.x, bid = blockIdx.x;
    if (bid == NPB) {                                 // ---- fold block ----
        if (tid < HIDDEN) {
            const float4* w1r = (const float4*)(W1 + (size_t)tid * 128);
            float a0 = 0.f, a1 = 0.f;
#pragma unroll 8
            for (int k4 = 0; k4 < 32; ++k4) {
                float4 v = w1r[k4];
                a0 += v.x * W2[8 * k4 + 0]; a1 += v.x * W2[8 * k4 + 1];
                a0 += v.y * W2[8 * k4 + 2]; a1 += v.y * W2[8 * k4 + 3];
                a0 += v.z * W2[8 * k4 + 4]; a1 += v.z * W2[8 * k4 + 5];
                a0 += v.w * W2[8 * k4 + 6]; a1 += v.w * W2[8 * k4 + 7];
            }
            W12[tid] = a0;                            // split layout: col0
            W12[HIDDEN + tid] = a1;                   // col1
            if (tid < 2) {
                float acc = b2[tid];
                for (int k = 0; k < 128; ++k) acc += b1[k] * W2[2 * k + tid];
                cvec[tid] = acc;
            }
        }
        return;
    }
    __shared__ int cursor[NB];
    for (int i = tid; i < NB; i += 1024) cursor[i] = 0;
    __syncthreads();
    const int e0 = bid * EPB, e1 = e0 + EPB;
    for (int e = e0 + tid; e < e1; e += 1024) {
        int d = ei[N_EDGES + e];
        int s = ei[e];
        float wv = ew[e];
        int bk = ((unsigned)d) >> BSH;
        int pos = atomicAdd(&cursor[bk], 1);          // block-local LDS cursor
        if (pos < SLOTS)                              // ~4e-13 per pair
            rec[((size_t)bk * NPB + bid) * SLOTS + pos] =
                make_uint2((unsigned)s | ((unsigned)(d & (BNODES - 1)) << 17),
                           __float_as_uint(wv));
    }
    __syncthreads();
    for (int i = tid; i < NB; i += 1024)
        cnt[(size_t)i * NPB + bid] = min(cursor[i], SLOTS);   // covers ALL entries
}

// ---- K2: blocks 0..NZB-1: persistent double-buffered z (counted vmcnt,
//          loads never drain). blocks NZB..NZB+NB-1: deg -> dinv. ----
__global__ __launch_bounds__(256) void k_zdeg(
        const float* __restrict__ x, const float* __restrict__ W12,
        const uint2* __restrict__ rec, const int* __restrict__ cnt,
        float* __restrict__ z, float* __restrict__ dinv) {
    __shared__ float tile[4][2][4][RPAD];             // 33280 B: [wave][buf][row][feat]
    __shared__ float acc[BNODES];
    const int tid = threadIdx.x, bid = blockIdx.x;
    if (bid < NZB) {
        const int wv   = tid >> 6;
        const int lane = tid & 63;
        const int sub  = lane & 15;                   // 16 lanes per row
        const int nl   = lane >> 4;                   // row within chunk (0..3)
        // weights for float4-slots {sub + 16j}: 2-way bank alias on LDS reads (free)
        float4 wa[4], wb[4];
#pragma unroll
        for (int j = 0; j < 4; ++j) {
            wa[j] = *(const float4*)(W12 + (sub + 16 * j) * 4);
            wb[j] = *(const float4*)(W12 + HIDDEN + (sub + 16 * j) * 4);
        }
        const int c0   = (bid * 4 + wv) * CPW;
        const int cend = (c0 + CPW < NCH) ? c0 + CPW : NCH;
        if (c0 < cend) {
            // stage first chunk into buf 0
#pragma unroll
            for (int j = 0; j < 4; ++j) {
                const float* gsrc = x + (size_t)(c0 * 4 + j) * HIDDEN + lane * 4;
                __builtin_amdgcn_global_load_lds(
                    (const __attribute__((address_space(1))) void*)gsrc,
                    (__attribute__((address_space(3))) void*)&tile[wv][0][j][0],
                    16, 0, 0);
            }
            int buf = 0;
            for (int c = c0; c < cend; ++c) {
                const bool more = (c + 1 < cend);
                if (more) {                           // stage next BEFORE waiting
#pragma unroll
                    for (int j = 0; j < 4; ++j) {
                        const float* gsrc = x + (size_t)((c + 1) * 4 + j) * HIDDEN + lane * 4;
                        __builtin_amdgcn_global_load_lds(
                            (const __attribute__((address_space(1))) void*)gsrc,
                            (__attribute__((address_space(3))) void*)&tile[wv][buf ^ 1][j][0],
                            16, 0, 0);
                    }
                    asm volatile("s_waitcnt vmcnt(4)" ::: "memory");  // current buf ready
                } else {
                    asm volatile("s_waitcnt vmcnt(0)" ::: "memory");
                }
                __builtin_amdgcn_sched_barrier(0);
                float a0 = 0.f, a1 = 0.f;
#pragma unroll
                for (int j = 0; j < 4; ++j) {
                    const float4 v = *(const float4*)&tile[wv][buf][nl][(sub + 16 * j) * 4];
                    a0 += v.x * wa[j].x + v.y * wa[j].y + v.z * wa[j].z + v.w * wa[j].w;
                    a1 += v.x * wb[j].x + v.y * wb[j].y + v.z * wb[j].z + v.w * wb[j].w;
                }
#pragma unroll
                for (int m = 1; m <= 8; m <<= 1) {    // reduce across 16 subs
                    a0 += __shfl_xor(a0, m, 64);
                    a1 += __shfl_xor(a1, m, 64);
                }
                if (sub == 0) ((float2*)z)[c * 4 + nl] = make_float2(a0, a1);
                buf ^= 1;
            }
        }
    } else {
        // ---------- deg for bucket, one thread per sub-chunk, paired loads ----------
        const int b = bid - NZB;
        if (tid < BNODES) acc[tid] = 1.0f;            // self-loop w=1
        __syncthreads();
        const int n = cnt[(size_t)b * NPB + tid];     // coalesced
        const uint2* r = rec + ((size_t)b * NPB + tid) * SLOTS;   // 256B-aligned
        int i = 0;
        for (; i + 2 <= n; i += 2) {
            uint4 q = *(const uint4*)(r + i);
            atomicAdd(&acc[q.x >> 17], __uint_as_float(q.y));
            atomicAdd(&acc[q.z >> 17], __uint_as_float(q.w));
        }
        if (i < n) {
            uint2 q = r[i];
            atomicAdd(&acc[q.x >> 17], __uint_as_float(q.y));
        }
        __syncthreads();
        if (tid < BNODES) {
            int node = b * BNODES + tid;
            if (node < N_NODES) dinv[node] = rsqrtf(acc[tid]);  // deg >= 1
        }
    }
}

// ---- K3: gather, one thread per sub-chunk, 2-wide unroll (4 gathers in flight);
//          flush fuses self-loop + bias ----
__global__ __launch_bounds__(256) void k_gather(
        const uint2* __restrict__ rec, const int* __restrict__ cnt,
        const float* __restrict__ dinv, const float* __restrict__ z,
        const float* __restrict__ cvec, float2* __restrict__ out) {
    __shared__ float ax[BNODES], ay[BNODES];
    const int tid = threadIdx.x, b = blockIdx.x;
    if (tid < BNODES) { ax[tid] = 0.f; ay[tid] = 0.f; }
    __syncthreads();
    const int n = cnt[(size_t)b * NPB + tid];             // coalesced
    const uint2* r = rec + ((size_t)b * NPB + tid) * SLOTS;
    int i = 0;
    for (; i + 2 <= n; i += 2) {
        uint4 q = *(const uint4*)(r + i);
        int s0 = (int)(q.x & 0x1FFFFu), s1 = (int)(q.z & 0x1FFFFu);
        float di0 = dinv[s0], di1 = dinv[s1];             // independent gathers
        float2 z0 = ((const float2*)z)[s0];
        float2 z1 = ((const float2*)z)[s1];
        float nw0 = di0 * __uint_as_float(q.y);
        float nw1 = di1 * __uint_as_float(q.w);
        int d0 = (int)(q.x >> 17), d1 = (int)(q.z >> 17);
        atomicAdd(&ax[d0], nw0 * z0.x);
        atomicAdd(&ay[d0], nw0 * z0.y);
        atomicAdd(&ax[d1], nw1 * z1.x);
        atomicAdd(&ay[d1], nw1 * z1.y);
    }
    if (i < n) {
        uint2 q = r[i];
        int s = (int)(q.x & 0x1FFFFu);
        float nw = dinv[s] * __uint_as_float(q.y);
        float2 zv = ((const float2*)z)[s];
        int dl = (int)(q.x >> 17);
        atomicAdd(&ax[dl], nw * zv.x);
        atomicAdd(&ay[dl], nw * zv.y);
    }
    __syncthreads();
    if (tid < BNODES) {
        int node = b * BNODES + tid;
        if (node < N_NODES) {
            float di = dinv[node];
            float2 zv = ((const float2*)z)[node];
            out[node] = make_float2(di * ax[tid] + di * di * zv.x + cvec[0],
                                    di * ay[tid] + di * di * zv.y + cvec[1]);
        }
    }
}

extern "C" void kernel_launch(void* const* d_in, const int* in_sizes, int n_in,
                              void* d_out, int out_size, void* d_ws, size_t ws_size,
                              hipStream_t stream) {
    const float* x  = (const float*)d_in[0];
    const int*   ei = (const int*)d_in[1];
    const float* ew = (const float*)d_in[2];
    const float* W1 = (const float*)d_in[3];
    const float* b1 = (const float*)d_in[4];
    const float* W2 = (const float*)d_in[5];
    const float* b2 = (const float*)d_in[6];
    float2* out = (float2*)d_out;

    char* ws = (char*)d_ws;
    uint2*  rec  = (uint2*)ws;           size_t off = (size_t)NB * NPB * SLOTS * 8;  // 51,249,152
    int*    cnt  = (int*)(ws + off);     off += (size_t)NB * NPB * 4;                // 800,768
    float*  dinv = (float*)(ws + off);   off += (size_t)N_NODES * 4;
    float*  z    = (float*)(ws + off);   off += (size_t)N_NODES * 8;
    float*  W12  = (float*)(ws + off);   off += HIDDEN * 2 * 4;
    float*  cvec = (float*)(ws + off);   off += 16;

    k_place <<<NPB + 1, 1024, 0, stream>>>(ei, ew, W1, b1, W2, b2, cnt, rec, W12, cvec);
    k_zdeg  <<<NZB + NB, 256, 0, stream>>>(x, W12, rec, cnt, z, dinv);
    k_gather<<<NB, 256, 0, stream>>>(rec, cnt, dinv, z, cvec, out);
}

// Round 19
// 78.090 us; speedup vs baseline: 1.0219x; 1.0219x over previous
//
#include <hip/hip_runtime.h>

#define N_NODES 100000
#define N_EDGES 1600000
#define HIDDEN 256

#define BSH 7                    // bucket = dst >> 7
#define BNODES 128               // nodes per bucket
#define NB 782                   // ceil(100000 / 128)
#define NPB 256                  // place blocks == sub-chunks per bucket == consumer block size
#define EPB 6250                 // edges per place block (256*6250 = 1.6M exact)
#define SLOTS 32                 // slots per (bucket, pblock): mean 8, P(ovf)~4e-13/pair
#define NZB 1024                 // z blocks: 4096 persistent waves, grid-stride over row pairs
#define NZW (NZB * 4)            // 4096 waves

typedef float f32x4 __attribute__((ext_vector_type(4)));

// rec layout: [bucket][pblock][slot], 8B records {src(17b) | dstloc(7b)<<17, w}
// cnt layout: [bucket][pblock]  -> consumers read coalesced; fully overwritten each call

// ---- K1: place (blocks 0..255) + W12/cvec fold (block 256) ----
__global__ __launch_bounds__(1024) void k_place(
        const int* __restrict__ ei, const float* __restrict__ ew,
        const float* __restrict__ W1, const float* __restrict__ b1,
        const float* __restrict__ W2, const float* __restrict__ b2,
        int* __restrict__ cnt, uint2* __restrict__ rec,
        float* __restrict__ W12, float* __restrict__ cvec) {
    const int tid = threadIdx.x, bid = blockIdx.x;
    if (bid == NPB) {                                 // ---- fold block ----
        if (tid < HIDDEN) {
            const float4* w1r = (const float4*)(W1 + (size_t)tid * 128);
            float a0 = 0.f, a1 = 0.f;
#pragma unroll 8
            for (int k4 = 0; k4 < 32; ++k4) {
                float4 v = w1r[k4];
                a0 += v.x * W2[8 * k4 + 0]; a1 += v.x * W2[8 * k4 + 1];
                a0 += v.y * W2[8 * k4 + 2]; a1 += v.y * W2[8 * k4 + 3];
                a0 += v.z * W2[8 * k4 + 4]; a1 += v.z * W2[8 * k4 + 5];
                a0 += v.w * W2[8 * k4 + 6]; a1 += v.w * W2[8 * k4 + 7];
            }
            W12[2 * tid] = a0; W12[2 * tid + 1] = a1;
            if (tid < 2) {
                float acc = b2[tid];
                for (int k = 0; k < 128; ++k) acc += b1[k] * W2[2 * k + tid];
                cvec[tid] = acc;
            }
        }
        return;
    }
    __shared__ int cursor[NB];
    for (int i = tid; i < NB; i += 1024) cursor[i] = 0;
    __syncthreads();
    const int e0 = bid * EPB, e1 = e0 + EPB;
    for (int e = e0 + tid; e < e1; e += 1024) {
        int d = ei[N_EDGES + e];
        int s = ei[e];
        float wv = ew[e];
        int bk = ((unsigned)d) >> BSH;
        int pos = atomicAdd(&cursor[bk], 1);          // block-local LDS cursor
        if (pos < SLOTS)                              // ~4e-13 per pair
            rec[((size_t)bk * NPB + bid) * SLOTS + pos] =
                make_uint2((unsigned)s | ((unsigned)(d & (BNODES - 1)) << 17),
                           __float_as_uint(wv));
    }
    __syncthreads();
    for (int i = tid; i < NB; i += 1024)
        cnt[(size_t)i * NPB + bid] = min(cursor[i], SLOTS);   // covers ALL entries
}

// ---- K2: blocks 0..NB-1: deg -> dinv.  blocks NB..NB+NZB-1: z = x@W12 as a
//      persistent grid-stride stream (copy-shaped schedule, nontemporal loads). ----
__global__ __launch_bounds__(256) void k_zdeg(
        const float* __restrict__ x, const float* __restrict__ W12,
        const uint2* __restrict__ rec, const int* __restrict__ cnt,
        float* __restrict__ z, float* __restrict__ dinv) {
    __shared__ float acc[BNODES];
    const int tid = threadIdx.x, bid = blockIdx.x;
    if (bid < NB) {
        // ---------- deg for bucket bid, one thread per sub-chunk ----------
        if (tid < BNODES) acc[tid] = 1.0f;            // self-loop w=1
        __syncthreads();
        const int n = cnt[(size_t)bid * NPB + tid];   // coalesced
        const uint2* r = rec + ((size_t)bid * NPB + tid) * SLOTS;
        int i = 0;
        for (; i + 2 <= n; i += 2) {
            uint4 q = *(const uint4*)(r + i);
            atomicAdd(&acc[q.x >> 17], __uint_as_float(q.y));
            atomicAdd(&acc[q.z >> 17], __uint_as_float(q.w));
        }
        if (i < n) {
            uint2 q = r[i];
            atomicAdd(&acc[q.x >> 17], __uint_as_float(q.y));
        }
        __syncthreads();
        if (tid < BNODES) {
            int node = bid * BNODES + tid;
            if (node < N_NODES) dinv[node] = rsqrtf(acc[tid]);  // deg >= 1
        }
    } else {
        // ---------- z: persistent grid-stride over row pairs ----------
        const int lane = tid & 63;
        const float2 w0 = ((const float2*)W12)[lane * 4 + 0];
        const float2 w1 = ((const float2*)W12)[lane * 4 + 1];
        const float2 w2 = ((const float2*)W12)[lane * 4 + 2];
        const float2 w3 = ((const float2*)W12)[lane * 4 + 3];
        const int g = (bid - NB) * 4 + (tid >> 6);    // wave id 0..NZW-1
        for (int p = g; p < N_NODES / 2; p += NZW) {  // row pair {2p, 2p+1}
            const float* base = x + (size_t)(2 * p) * HIDDEN + lane * 4;
            f32x4 xa = __builtin_nontemporal_load((const f32x4*)base);
            f32x4 xb = __builtin_nontemporal_load((const f32x4*)(base + HIDDEN));
            float a0 = xa.x * w0.x + xa.y * w1.x + xa.z * w2.x + xa.w * w3.x;
            float a1 = xa.x * w0.y + xa.y * w1.y + xa.z * w2.y + xa.w * w3.y;
            float c0 = xb.x * w0.x + xb.y * w1.x + xb.z * w2.x + xb.w * w3.x;
            float c1 = xb.x * w0.y + xb.y * w1.y + xb.z * w2.y + xb.w * w3.y;
#pragma unroll
            for (int m = 1; m <= 32; m <<= 1) {       // 4 independent chains
                a0 += __shfl_xor(a0, m, 64);
                a1 += __shfl_xor(a1, m, 64);
                c0 += __shfl_xor(c0, m, 64);
                c1 += __shfl_xor(c1, m, 64);
            }
            if (lane == 0) *(float4*)(z + 4 * p) = make_float4(a0, a1, c0, c1);
        }
    }
}

// ---- K3: gather, one thread per sub-chunk; per record gather dinv[src], z[src];
//          flush fuses self-loop + bias ----
__global__ __launch_bounds__(256) void k_gather(
        const uint2* __restrict__ rec, const int* __restrict__ cnt,
        const float* __restrict__ dinv, const float* __restrict__ z,
        const float* __restrict__ cvec, float2* __restrict__ out) {
    __shared__ float ax[BNODES], ay[BNODES];
    const int tid = threadIdx.x, b = blockIdx.x;
    if (tid < BNODES) { ax[tid] = 0.f; ay[tid] = 0.f; }
    __syncthreads();
    const int n = cnt[(size_t)b * NPB + tid];             // coalesced
    const uint2* r = rec + ((size_t)b * NPB + tid) * SLOTS;
    int i = 0;
    for (; i + 2 <= n; i += 2) {
        uint4 q = *(const uint4*)(r + i);
        int s0 = (int)(q.x & 0x1FFFFu), s1 = (int)(q.z & 0x1FFFFu);
        float di0 = dinv[s0], di1 = dinv[s1];             // independent gathers
        float2 z0 = ((const float2*)z)[s0];
        float2 z1 = ((const float2*)z)[s1];
        float nw0 = di0 * __uint_as_float(q.y);
        float nw1 = di1 * __uint_as_float(q.w);
        int d0 = (int)(q.x >> 17), d1 = (int)(q.z >> 17);
        atomicAdd(&ax[d0], nw0 * z0.x);
        atomicAdd(&ay[d0], nw0 * z0.y);
        atomicAdd(&ax[d1], nw1 * z1.x);
        atomicAdd(&ay[d1], nw1 * z1.y);
    }
    if (i < n) {
        uint2 q = r[i];
        int s = (int)(q.x & 0x1FFFFu);
        float nw = dinv[s] * __uint_as_float(q.y);
        float2 zv = ((const float2*)z)[s];
        int dl = (int)(q.x >> 17);
        atomicAdd(&ax[dl], nw * zv.x);
        atomicAdd(&ay[dl], nw * zv.y);
    }
    __syncthreads();
    if (tid < BNODES) {
        int node = b * BNODES + tid;
        if (node < N_NODES) {
            float di = dinv[node];
            float2 zv = ((const float2*)z)[node];
            out[node] = make_float2(di * ax[tid] + di * di * zv.x + cvec[0],
                                    di * ay[tid] + di * di * zv.y + cvec[1]);
        }
    }
}

extern "C" void kernel_launch(void* const* d_in, const int* in_sizes, int n_in,
                              void* d_out, int out_size, void* d_ws, size_t ws_size,
                              hipStream_t stream) {
    const float* x  = (const float*)d_in[0];
    const int*   ei = (const int*)d_in[1];
    const float* ew = (const float*)d_in[2];
    const float* W1 = (const float*)d_in[3];
    const float* b1 = (const float*)d_in[4];
    const float* W2 = (const float*)d_in[5];
    const float* b2 = (const float*)d_in[6];
    float2* out = (float2*)d_out;

    char* ws = (char*)d_ws;
    uint2*  rec  = (uint2*)ws;           size_t off = (size_t)NB * NPB * SLOTS * 8;  // 51,249,152
    int*    cnt  = (int*)(ws + off);     off += (size_t)NB * NPB * 4;                // 800,768
    float*  dinv = (float*)(ws + off);   off += (size_t)N_NODES * 4;
    float*  z    = (float*)(ws + off);   off += (size_t)N_NODES * 8;
    float*  W12  = (float*)(ws + off);   off += HIDDEN * 2 * 4;
    float*  cvec = (float*)(ws + off);   off += 16;

    k_place <<<NPB + 1, 1024, 0, stream>>>(ei, ew, W1, b1, W2, b2, cnt, rec, W12, cvec);
    k_zdeg  <<<NB + NZB, 256, 0, stream>>>(x, W12, rec, cnt, z, dinv);
    k_gather<<<NB, 256, 0, stream>>>(rec, cnt, dinv, z, cvec, out);
}